// Round 7
// baseline (593.100 us; speedup 1.0000x reference)
//
#include <hip/hip_runtime.h>
#include <hip/hip_bf16.h>
#include <stdint.h>

#define N    8192
#define D    256
#define NCLS 100

static constexpr float TEMP    = 0.5f;
static constexpr float SCALE_F = 1.69864360f;  // sqrt(log2e/TEMP)
static constexpr float LN2     = 0.69314718055994531f;

// Per-band partial slots: 64 bands x 130 slots x 128 rows (see simexp).
#define NSLOT 130
#define DIAG_REPS 10

typedef float f32x4 __attribute__((ext_vector_type(4)));

__device__ __forceinline__ unsigned short f2bf(float f) {
  union { float f; unsigned int u; } x; x.f = f;
  unsigned int r = x.u + 0x7fffu + ((x.u >> 16) & 1u);
  return (unsigned short)(r >> 16);
}
__device__ __forceinline__ float bf2f(unsigned short b) {
  union { unsigned int u; float f; } x; x.u = ((unsigned int)b) << 16;
  return x.f;
}
__device__ __forceinline__ void gld16(const void* g, void* l) {
  __builtin_amdgcn_global_load_lds(
      (const __attribute__((address_space(1))) unsigned int*)g,
      (__attribute__((address_space(3))) unsigned int*)l, 16, 0, 0);
}

// fp8 fragment-major layout:
//   addr(r, k) = (r>>4)*4096 + (k>>3)*128 + (r&15)*8 + (k&7)

// ---- Kernel A: row-normalize; bf16 row-major copy (class sums) + fp8 e4m3
// fragment-major copy (GEMM).
__global__ __launch_bounds__(256) void normalize_kernel(
    const float* __restrict__ emb, const long long* __restrict__ label,
    unsigned short* __restrict__ abf, unsigned char* __restrict__ a8,
    int* __restrict__ cnt, int* __restrict__ list) {
  const int row  = blockIdx.x * 4 + (threadIdx.x >> 6);
  const int lane = threadIdx.x & 63;
  const float4 v = ((const float4*)(emb + (size_t)row * D))[lane];
  float ss = v.x * v.x + v.y * v.y + v.z * v.z + v.w * v.w;
#pragma unroll
  for (int off = 1; off < 64; off <<= 1) ss += __shfl_xor(ss, off);
  const float s = rsqrtf(ss) * SCALE_F;
  const float x = v.x * s, y = v.y * s, z = v.z * s, wv = v.w * s;

  ushort4 o;
  o.x = f2bf(x); o.y = f2bf(y); o.z = f2bf(z); o.w = f2bf(wv);
  ((ushort4*)(abf + (size_t)row * D))[lane] = o;

  int p = __builtin_amdgcn_cvt_pk_fp8_f32(x, y, 0, false);
  p = __builtin_amdgcn_cvt_pk_fp8_f32(z, wv, p, true);
  *(int*)(a8 + (size_t)(row >> 4) * 4096 + (lane >> 1) * 128 +
          (row & 15) * 8 + (lane & 1) * 4) = p;

  if (lane == 0) {
    const int c = (int)label[row];
    const int slot = atomicAdd(cnt + c, 1);
    list[c * 256 + slot] = row;
  }
}

// ---- shared helpers for the GEMM block (used by real + diag kernels) ----
struct TileCoord { int x, y; };
__device__ __forceinline__ TileCoord tri_decode(int b) {
  int x = (int)((-1.0f + sqrtf(1.0f + 8.0f * (float)b)) * 0.5f);
  while ((x + 1) * (x + 2) / 2 <= b) ++x;
  while (x * (x + 1) / 2 > b) --x;
  return {x, b - x * (x + 1) / 2};
}

__device__ __forceinline__ void stage_tiles(const unsigned char* __restrict__ A,
                                            unsigned char* sa,
                                            unsigned char* sb, int row0,
                                            int col0, int w, int lane) {
#pragma unroll
  for (int p = 0; p < 8; ++p) {
    const int seg = w * 8 + p;  // wave-uniform
    gld16(A + (size_t)((row0 >> 4) + (seg >> 2)) * 4096 + (seg & 3) * 1024 +
              lane * 16,
          sa + seg * 1024);
    gld16(A + (size_t)((col0 >> 4) + (seg >> 2)) * 4096 + (seg & 3) * 1024 +
              lane * 16,
          sb + seg * 1024);
  }
}

__device__ __forceinline__ void compute_acc(const unsigned char* sa,
                                            const unsigned char* sb, int pam,
                                            int pbn, int quad, int l15,
                                            f32x4 acc[4][4]) {
#pragma unroll
  for (int mt = 0; mt < 4; ++mt)
#pragma unroll
    for (int nt = 0; nt < 4; ++nt) acc[mt][nt] = (f32x4){0.f, 0.f, 0.f, 0.f};
#pragma unroll
  for (int kq = 0; kq < 4; ++kq) {
#pragma unroll
    for (int kkl = 0; kkl < 2; ++kkl) {
      const int fo = kq * 1024 + (kkl * 4 + quad) * 128 + l15 * 8;
      long af[4], bf[4];
#pragma unroll
      for (int mt = 0; mt < 4; ++mt)
        af[mt] = *(const long*)(sa + (pam + mt) * 4096 + fo);
#pragma unroll
      for (int nt = 0; nt < 4; ++nt)
        bf[nt] = *(const long*)(sb + (pbn + nt) * 4096 + fo);
#pragma unroll
      for (int mt = 0; mt < 4; ++mt)
#pragma unroll
        for (int nt = 0; nt < 4; ++nt)
          acc[mt][nt] = __builtin_amdgcn_mfma_f32_16x16x32_fp8_fp8(
              af[mt], bf[nt], acc[mt][nt], 0, 0, 0);
    }
  }
}

// ---- Kernel B (REAL, unchanged from R6): symmetric strict-upper triangle,
// one block per live 128x128 sub-tile, async LDS staging, single drain,
// bijective partial stores (no atomics).
__global__ __launch_bounds__(256, 2) void simexp_rowsum_kernel(
    const unsigned char* __restrict__ A, float* __restrict__ part) {
  __shared__ __align__(16) unsigned char sa[128 * 256];
  __shared__ __align__(16) unsigned char sb[128 * 256];
  const int tid  = threadIdx.x;
  const int w    = tid >> 6;
  const int lane = tid & 63;
  const int quad = lane >> 4;
  const int l15  = lane & 15;

  const TileCoord tc = tri_decode(blockIdx.x);
  const int x = tc.x, y = tc.y;
  const int row0 = y << 7;
  const int col0 = x << 7;
  const bool diag = (x == y);
  const int wm  = (w & 1) * 64;
  const int jn0 = (w >> 1) * 64;

  stage_tiles(A, sa, sb, row0, col0, w, lane);
  __syncthreads();

  if (diag && wm > jn0) {
    part[((size_t)y * NSLOT + 2 * x) * 128 + 64 + lane] = 0.f;
    part[((size_t)x * NSLOT + 129) * 128 + lane] = 0.f;
    return;
  }
  const bool needmask = diag && (wm == jn0);
  const int pam = (w & 1) * 4;
  const int pbn = (w >> 1) * 4;

  f32x4 acc[4][4];
  compute_acc(sa, sb, pam, pbn, quad, l15, acc);

  float rowpart[4][4];
  float colpart[4] = {0.f, 0.f, 0.f, 0.f};
#pragma unroll
  for (int mt = 0; mt < 4; ++mt)
#pragma unroll
    for (int e = 0; e < 4; ++e) rowpart[mt][e] = 0.f;
#pragma unroll
  for (int mt = 0; mt < 4; ++mt)
#pragma unroll
    for (int nt = 0; nt < 4; ++nt)
#pragma unroll
      for (int e = 0; e < 4; ++e) {
        float v = __builtin_amdgcn_exp2f(acc[mt][nt][e]);
        if (needmask) {
          const int iw = mt * 16 + quad * 4 + e;
          const int jw = nt * 16 + l15;
          v = (iw < jw) ? v : 0.f;
        }
        rowpart[mt][e] += v;
        colpart[nt] += v;
      }

  const int rslot = 2 * x + (jn0 >> 6);
  const int cslot = diag ? (128 + (wm >> 6)) : (2 * y + (wm >> 6));
  float* rowdst = part + ((size_t)y * NSLOT + rslot) * 128 + wm;
  float* coldst = part + ((size_t)x * NSLOT + cslot) * 128 + jn0;

#pragma unroll
  for (int nt = 0; nt < 4; ++nt) {
    float v = colpart[nt];
    v += __shfl_xor(v, 16);
    v += __shfl_xor(v, 32);
    if (quad == 0) coldst[nt * 16 + l15] = v;
  }
#pragma unroll
  for (int mt = 0; mt < 4; ++mt)
#pragma unroll
    for (int e = 0; e < 4; ++e) {
      float v = rowpart[mt][e];
      v += __shfl_xor(v, 1);
      v += __shfl_xor(v, 2);
      v += __shfl_xor(v, 4);
      v += __shfl_xor(v, 8);
      if (l15 == 0) rowdst[mt * 16 + quad * 4 + e] = v;
    }
}

// ---- DIAGNOSTIC ablation kernels (results discarded; asm keeps work live).
// MODE 1: rep{ stage + barrier }                      -> S (stage cost)
// MODE 2: stage once; rep{ k-loop MFMA }              -> C (pure compute)
// MODE 3: rep{ stage; bar; k-loop; bar }              -> S与C overlap
// MODE 4: MODE 3 + exp2/shfl epilogue                 -> +E
template <int MODE>
__global__ __launch_bounds__(256, 2) void simexp_diag_kernel(
    const unsigned char* __restrict__ A) {
  __shared__ __align__(16) unsigned char sa[128 * 256];
  __shared__ __align__(16) unsigned char sb[128 * 256];
  const int tid  = threadIdx.x;
  const int w    = tid >> 6;
  const int lane = tid & 63;
  const int quad = lane >> 4;
  const int l15  = lane & 15;

  const TileCoord tc = tri_decode(blockIdx.x);
  const int x = tc.x, y = tc.y;
  const int row0 = y << 7;
  const int col0 = x << 7;
  const bool needmask = (x == y) && ((w & 1) * 64 == (w >> 1) * 64);
  const int pam = (w & 1) * 4;
  const int pbn = (w >> 1) * 4;

  float keep = 0.f;

  if constexpr (MODE == 2) {
    stage_tiles(A, sa, sb, row0, col0, w, lane);
    __syncthreads();
  }

#pragma unroll 1
  for (int r = 0; r < DIAG_REPS; ++r) {
    if constexpr (MODE != 2) {
      stage_tiles(A, sa, sb, row0, col0, w, lane);
      __syncthreads();
    }
    if constexpr (MODE >= 2) {
      f32x4 acc[4][4];
      compute_acc(sa, sb, pam, pbn, quad, l15, acc);
      if constexpr (MODE == 4) {
        float rowpart[4][4];
        float colpart[4] = {0.f, 0.f, 0.f, 0.f};
#pragma unroll
        for (int mt = 0; mt < 4; ++mt)
#pragma unroll
          for (int e = 0; e < 4; ++e) rowpart[mt][e] = 0.f;
#pragma unroll
        for (int mt = 0; mt < 4; ++mt)
#pragma unroll
          for (int nt = 0; nt < 4; ++nt)
#pragma unroll
            for (int e = 0; e < 4; ++e) {
              float v = __builtin_amdgcn_exp2f(acc[mt][nt][e]);
              if (needmask) {
                const int iw = mt * 16 + quad * 4 + e;
                const int jw = nt * 16 + l15;
                v = (iw < jw) ? v : 0.f;
              }
              rowpart[mt][e] += v;
              colpart[nt] += v;
            }
#pragma unroll
        for (int nt = 0; nt < 4; ++nt) {
          float v = colpart[nt];
          v += __shfl_xor(v, 16);
          v += __shfl_xor(v, 32);
          keep += v;
        }
#pragma unroll
        for (int mt = 0; mt < 4; ++mt)
#pragma unroll
          for (int e = 0; e < 4; ++e) {
            float v = rowpart[mt][e];
            v += __shfl_xor(v, 1);
            v += __shfl_xor(v, 2);
            v += __shfl_xor(v, 4);
            v += __shfl_xor(v, 8);
            keep += v;
          }
      } else {
        // keep MFMA results live without epilogue
#pragma unroll
        for (int mt = 0; mt < 4; ++mt)
#pragma unroll
          for (int nt = 0; nt < 4; ++nt)
            asm volatile("" ::"v"(acc[mt][nt]));
      }
    }
    if constexpr (MODE == 3 || MODE == 4) __syncthreads();
  }
  asm volatile("" ::"v"(keep));
}

__global__ __launch_bounds__(256) void finalize_kernel(
    const unsigned short* __restrict__ abf, const float* __restrict__ part,
    const long long* __restrict__ label, const int* __restrict__ cnt,
    const int* __restrict__ list, float* __restrict__ out) {
  __shared__ float red[4];
  __shared__ int rows_l[256];
  const int tid  = threadIdx.x;
  const int w    = tid >> 6;
  const int lane = tid & 63;

  if (blockIdx.x < NCLS) {
    const int c = blockIdx.x;
    const int m = cnt[c];
    if (m <= 1) return;
    if (tid < m) rows_l[tid] = list[c * 256 + tid];
    __syncthreads();
    float acc = 0.f;
    for (int s = 0; s < m; ++s)
      acc += bf2f(abf[(size_t)rows_l[s] * D + tid]);
    float v = acc * acc;
#pragma unroll
    for (int off = 1; off < 64; off <<= 1) v += __shfl_xor(v, off);
    if (lane == 0) red[w] = v;
    __syncthreads();
    if (tid == 0) {
      const float ssq = red[0] + red[1] + red[2] + red[3];
      const float term = (ssq * LN2 - 2.0f * (float)m) / (float)(m - 1);
      atomicAdd(out, -term);
    }
  } else {
    const int i = (blockIdx.x - NCLS) * 256 + tid;
    const int band = i >> 7, r = i & 127;
    const float* ps = part + (size_t)band * NSLOT * 128 + r;
    float rs = 0.f;
#pragma unroll 13
    for (int s = 0; s < NSLOT; ++s) rs += ps[(size_t)s * 128];
    const int c = (int)label[i];
    float v = 0.f;
    if (cnt[c] > 1)
      v = __builtin_amdgcn_logf(rs) * LN2;
#pragma unroll
    for (int off = 1; off < 64; off <<= 1) v += __shfl_xor(v, off);
    if (lane == 0) red[w] = v;
    __syncthreads();
    if (tid == 0)
      atomicAdd(out, red[0] + red[1] + red[2] + red[3]);
  }
}

extern "C" void kernel_launch(void* const* d_in, const int* in_sizes, int n_in,
                              void* d_out, int out_size, void* d_ws,
                              size_t ws_size, hipStream_t stream) {
  const float* emb = (const float*)d_in[0];
  const long long* label = (const long long*)d_in[1];
  float* out = (float*)d_out;

  char* ws = (char*)d_ws;
  unsigned short* abf = (unsigned short*)ws;            // 4 MB bf16 row-major
  unsigned char* a8 = (unsigned char*)(ws + (size_t)N * D * 2);  // 2 MB fp8
  float* part = (float*)(ws + (size_t)N * D * 3);       // 64*130*128 f32
  int* cnt = (int*)(ws + (size_t)N * D * 3 + (size_t)64 * NSLOT * 128 * 4);
  int* list = cnt + 128;                                // NCLS*256 ints

  hipMemsetAsync(cnt, 0, 128 * 4, stream);
  hipMemsetAsync(out, 0, sizeof(float), stream);

  normalize_kernel<<<N / 4, 256, 0, stream>>>(emb, label, abf, a8, cnt, list);
  simexp_rowsum_kernel<<<2080, 256, 0, stream>>>(a8, part);
  finalize_kernel<<<NCLS + N / 256, 256, 0, stream>>>(abf, part, label, cnt,
                                                      list, out);

  // ---- diagnostic ablation dispatches (results discarded; timing only) ----
  simexp_diag_kernel<1><<<2080, 256, 0, stream>>>(a8);
  simexp_diag_kernel<2><<<2080, 256, 0, stream>>>(a8);
  simexp_diag_kernel<3><<<2080, 256, 0, stream>>>(a8);
  simexp_diag_kernel<4><<<2080, 256, 0, stream>>>(a8);
}

// Round 8
// 121.135 us; speedup vs baseline: 4.8962x; 4.8962x over previous
//
#include <hip/hip_runtime.h>
#include <hip/hip_bf16.h>
#include <stdint.h>

#define N    8192
#define D    256
#define NCLS 100

static constexpr float TEMP    = 0.5f;
static constexpr float SCALE_F = 1.69864360f;  // sqrt(log2e/TEMP)
static constexpr float LN2     = 0.69314718055994531f;

// Per-band partial slots: 64 bands x 130 slots x 128 rows (see simexp).
#define NSLOT 130

typedef float f32x4 __attribute__((ext_vector_type(4)));
typedef long  lx2  __attribute__((ext_vector_type(2)));

__device__ __forceinline__ unsigned short f2bf(float f) {
  union { float f; unsigned int u; } x; x.f = f;
  unsigned int r = x.u + 0x7fffu + ((x.u >> 16) & 1u);
  return (unsigned short)(r >> 16);
}
__device__ __forceinline__ float bf2f(unsigned short b) {
  union { unsigned int u; float f; } x; x.u = ((unsigned int)b) << 16;
  return x.f;
}

// fp8 fragment-PAIR-major layout (R8): for row r, k:
//   kq = k>>6, kl = k&63, kkl = kl>>5, q = (kl>>3)&3
//   addr = (r>>4)*4096 + kq*1024 + q*256 + (r&15)*16 + kkl*8 + (k&7)
// -> lane (quad,l15)'s A fragments for BOTH kkl halves of one kq are one
//    contiguous 16B: global_load_dwordx4, wave-contiguous 1024B segment.
//    The whole per-wave operand set is 4 panels x 4 kq x 16B = 128 VGPRs.

// ---- Kernel A: row-normalize; bf16 row-major copy (class sums) + fp8 e4m3
// fragment-pair-major copy (GEMM).
__global__ __launch_bounds__(256) void normalize_kernel(
    const float* __restrict__ emb, const long long* __restrict__ label,
    unsigned short* __restrict__ abf, unsigned char* __restrict__ a8,
    int* __restrict__ cnt, int* __restrict__ list) {
  const int row  = blockIdx.x * 4 + (threadIdx.x >> 6);
  const int lane = threadIdx.x & 63;
  const float4 v = ((const float4*)(emb + (size_t)row * D))[lane];
  float ss = v.x * v.x + v.y * v.y + v.z * v.z + v.w * v.w;
#pragma unroll
  for (int off = 1; off < 64; off <<= 1) ss += __shfl_xor(ss, off);
  const float s = rsqrtf(ss) * SCALE_F;
  const float x = v.x * s, y = v.y * s, z = v.z * s, wv = v.w * s;

  ushort4 o;
  o.x = f2bf(x); o.y = f2bf(y); o.z = f2bf(z); o.w = f2bf(wv);
  ((ushort4*)(abf + (size_t)row * D))[lane] = o;

  int p = __builtin_amdgcn_cvt_pk_fp8_f32(x, y, 0, false);
  p = __builtin_amdgcn_cvt_pk_fp8_f32(z, wv, p, true);
  // k0 = lane*4: kq=lane>>4, q=(lane>>1)&3, kkl=(lane>>3)&1, k&7=(lane&1)*4
  *(int*)(a8 + (size_t)(row >> 4) * 4096 + (lane >> 4) * 1024 +
          ((lane >> 1) & 3) * 256 + (row & 15) * 16 + ((lane >> 3) & 1) * 8 +
          (lane & 1) * 4) = p;

  if (lane == 0) {
    const int c = (int)label[row];
    const int slot = atomicAdd(cnt + c, 1);
    list[c * 256 + slot] = row;
  }
}

struct TileCoord { int x, y; };
__device__ __forceinline__ TileCoord tri_decode(int b) {
  int x = (int)((-1.0f + sqrtf(1.0f + 8.0f * (float)b)) * 0.5f);
  while ((x + 1) * (x + 2) / 2 <= b) ++x;
  while (x * (x + 1) / 2 > b) --x;
  return {x, b - x * (x + 1) / 2};
}

// ---- Kernel B: symmetric (strict upper triangle), one block per live
// 128x128 sub-tile (2080 blocks).
//
// R8 (in-register GEMM): R7's ablation proved the LDS-fed MFMA loop itself
// was the wall (slowest diag mode = 24.6 us/rep vs 8.5 us MFMA floor,
// MfmaUtil 30% at 2 waves/SIMD — ds_read latency un-hidable). Now the
// ENTIRE per-wave operand set (A 64 VGPR + B 64 VGPR) loads up-front as
// 32 back-to-back dwordx4 from L2 (MLP=32), then 128 MFMAs run pure-
// register with zero LDS, zero barriers, zero per-phase waits. The other
// co-resident block's load burst hides under this block's MFMA stream.
// launch_bounds(256,2) -> 256-VGPR cap (est ~220 used), 2 blocks/CU.
//
// Partial-sum slot map (bijective, plain stores, no atomics) — band t:
//   row-side, block (x,t), wave col-half jh -> slot 2x+jh   (slots 2t..127)
//   col-side, block (t,y<t), wave row-half rh -> slot 2y+rh (slots 0..2t-1)
//   col-side of diagonal block (t,t) -> slots 128+rh
// Every (band, slot, idx) written exactly once (diag dead wave writes 0s).
__global__ __launch_bounds__(256, 2) void simexp_rowsum_kernel(
    const unsigned char* __restrict__ A, float* __restrict__ part) {
  const int tid  = threadIdx.x;
  const int w    = tid >> 6;
  const int lane = tid & 63;
  const int quad = lane >> 4;
  const int l15  = lane & 15;

  const TileCoord tc = tri_decode(blockIdx.x);
  const int x = tc.x, y = tc.y;
  const int row0 = y << 7;
  const int col0 = x << 7;
  const bool diag = (x == y);
  const int wm  = (w & 1) * 64;   // wave's row half
  const int jn0 = (w >> 1) * 64;  // wave's col half

  // Diagonal sub-tile, wave region entirely strictly-lower (only w=1):
  // contributes nothing; fill its partial slots (coverage invariant).
  if (diag && wm > jn0) {
    part[((size_t)y * NSLOT + 2 * x) * 128 + 64 + lane] = 0.f;  // row-side
    part[((size_t)x * NSLOT + 129) * 128 + lane] = 0.f;         // col-side
    return;
  }
  const bool needmask = diag && (wm == jn0);

  const unsigned char* Ap = A + (size_t)((row0 >> 4) + (w & 1) * 4) * 4096;
  const unsigned char* Bp = A + (size_t)((col0 >> 4) + (w >> 1) * 4) * 4096;
  const int lo = quad * 256 + l15 * 16;

  // Load the full operand set into registers: 32 x dwordx4, all in flight.
  lx2 aF[4][4], bF[4][4];  // [panel][kq] -> {kkl0 frag, kkl1 frag}
#pragma unroll
  for (int mt = 0; mt < 4; ++mt)
#pragma unroll
    for (int kq = 0; kq < 4; ++kq)
      aF[mt][kq] = *(const lx2*)(Ap + mt * 4096 + kq * 1024 + lo);
#pragma unroll
  for (int nt = 0; nt < 4; ++nt)
#pragma unroll
    for (int kq = 0; kq < 4; ++kq)
      bF[nt][kq] = *(const lx2*)(Bp + nt * 4096 + kq * 1024 + lo);

  f32x4 acc[4][4];
#pragma unroll
  for (int mt = 0; mt < 4; ++mt)
#pragma unroll
    for (int nt = 0; nt < 4; ++nt) acc[mt][nt] = (f32x4){0.f, 0.f, 0.f, 0.f};

  // 128 pure-register MFMAs.
#pragma unroll
  for (int kq = 0; kq < 4; ++kq)
#pragma unroll
    for (int kkl = 0; kkl < 2; ++kkl)
#pragma unroll
      for (int mt = 0; mt < 4; ++mt)
#pragma unroll
        for (int nt = 0; nt < 4; ++nt)
          acc[mt][nt] = __builtin_amdgcn_mfma_f32_16x16x32_fp8_fp8(
              aF[mt][kq][kkl], bF[nt][kq][kkl], acc[mt][nt], 0, 0, 0);

  // Epilogue: exp2, diagonal mask, row partials + column partials.
  float rowpart[4][4];
  float colpart[4] = {0.f, 0.f, 0.f, 0.f};
#pragma unroll
  for (int mt = 0; mt < 4; ++mt)
#pragma unroll
    for (int e = 0; e < 4; ++e) rowpart[mt][e] = 0.f;
#pragma unroll
  for (int mt = 0; mt < 4; ++mt)
#pragma unroll
    for (int nt = 0; nt < 4; ++nt)
#pragma unroll
      for (int e = 0; e < 4; ++e) {
        float v = __builtin_amdgcn_exp2f(acc[mt][nt][e]);
        if (needmask) {
          const int iw = mt * 16 + quad * 4 + e;  // row within wave region
          const int jw = nt * 16 + l15;           // col within wave region
          v = (iw < jw) ? v : 0.f;
        }
        rowpart[mt][e] += v;
        colpart[nt] += v;
      }

  // Partial destinations (plain stores, each address written exactly once).
  const int rslot = 2 * x + (jn0 >> 6);
  const int cslot = diag ? (128 + (wm >> 6)) : (2 * y + (wm >> 6));
  float* rowdst = part + ((size_t)y * NSLOT + rslot) * 128 + wm;
  float* coldst = part + ((size_t)x * NSLOT + cslot) * 128 + jn0;

  // Column reduce over rows (lane bits 4,5): lanes quad==0 hold 16 cols.
#pragma unroll
  for (int nt = 0; nt < 4; ++nt) {
    float v = colpart[nt];
    v += __shfl_xor(v, 16);
    v += __shfl_xor(v, 32);
    if (quad == 0) coldst[nt * 16 + l15] = v;
  }
  // Row reduce over 16 cols (lane bits 0..3): lanes l15==0 (one per quad)
  // hold rows quad*4+e+mt*16.
#pragma unroll
  for (int mt = 0; mt < 4; ++mt)
#pragma unroll
    for (int e = 0; e < 4; ++e) {
      float v = rowpart[mt][e];
      v += __shfl_xor(v, 1);
      v += __shfl_xor(v, 2);
      v += __shfl_xor(v, 4);
      v += __shfl_xor(v, 8);
      if (l15 == 0) rowdst[mt * 16 + quad * 4 + e] = v;
    }
}

__global__ __launch_bounds__(256) void finalize_kernel(
    const unsigned short* __restrict__ abf, const float* __restrict__ part,
    const long long* __restrict__ label, const int* __restrict__ cnt,
    const int* __restrict__ list, float* __restrict__ out) {
  __shared__ float red[4];
  __shared__ int rows_l[256];
  const int tid  = threadIdx.x;
  const int w    = tid >> 6;
  const int lane = tid & 63;

  if (blockIdx.x < NCLS) {
    const int c = blockIdx.x;
    const int m = cnt[c];
    if (m <= 1) return;
    if (tid < m) rows_l[tid] = list[c * 256 + tid];
    __syncthreads();
    float acc = 0.f;
    for (int s = 0; s < m; ++s)
      acc += bf2f(abf[(size_t)rows_l[s] * D + tid]);
    float v = acc * acc;
#pragma unroll
    for (int off = 1; off < 64; off <<= 1) v += __shfl_xor(v, off);
    if (lane == 0) red[w] = v;
    __syncthreads();
    if (tid == 0) {
      const float ssq = red[0] + red[1] + red[2] + red[3];
      const float term = (ssq * LN2 - 2.0f * (float)m) / (float)(m - 1);
      atomicAdd(out, -term);
    }
  } else {
    // rowsum_i = sum of the 130 per-block partials for this row's band.
    const int i = (blockIdx.x - NCLS) * 256 + tid;
    const int band = i >> 7, r = i & 127;
    const float* ps = part + (size_t)band * NSLOT * 128 + r;
    float rs = 0.f;
#pragma unroll 13
    for (int s = 0; s < NSLOT; ++s) rs += ps[(size_t)s * 128];
    const int c = (int)label[i];
    float v = 0.f;
    if (cnt[c] > 1)
      v = __builtin_amdgcn_logf(rs) * LN2;
#pragma unroll
    for (int off = 1; off < 64; off <<= 1) v += __shfl_xor(v, off);
    if (lane == 0) red[w] = v;
    __syncthreads();
    if (tid == 0)
      atomicAdd(out, red[0] + red[1] + red[2] + red[3]);
  }
}

extern "C" void kernel_launch(void* const* d_in, const int* in_sizes, int n_in,
                              void* d_out, int out_size, void* d_ws,
                              size_t ws_size, hipStream_t stream) {
  const float* emb = (const float*)d_in[0];
  const long long* label = (const long long*)d_in[1];
  float* out = (float*)d_out;

  char* ws = (char*)d_ws;
  unsigned short* abf = (unsigned short*)ws;            // 4 MB bf16 row-major
  unsigned char* a8 = (unsigned char*)(ws + (size_t)N * D * 2);  // 2 MB fp8
  float* part = (float*)(ws + (size_t)N * D * 3);       // 64*130*128 f32
  int* cnt = (int*)(ws + (size_t)N * D * 3 + (size_t)64 * NSLOT * 128 * 4);
  int* list = cnt + 128;                                // NCLS*256 ints

  hipMemsetAsync(cnt, 0, 128 * 4, stream);
  hipMemsetAsync(out, 0, sizeof(float), stream);

  normalize_kernel<<<N / 4, 256, 0, stream>>>(emb, label, abf, a8, cnt, list);

  // One block per live upper-triangle 128x128 sub-tile: 64*65/2 = 2080.
  simexp_rowsum_kernel<<<2080, 256, 0, stream>>>(a8, part);

  finalize_kernel<<<NCLS + N / 256, 256, 0, stream>>>(abf, part, label, cnt,
                                                      list, out);
}